// Round 10
// baseline (269.547 us; speedup 1.0000x reference)
//
#include <hip/hip_runtime.h>
#include <hip/hip_fp16.h>

#define NLEVELS 16
#define LOG2T 19
#define TENTRIES (1u << LOG2T)
#define TMASK (TENTRIES - 1u)
#define PRIME1 2654435761u
#define THREADS 256
#define PTS_PER_THREAD 4
#define PTS_PER_BLOCK (THREADS * PTS_PER_THREAD)

// int8 quantization scale: tables are uniform(-1e-4, 1e-4) per problem spec
#define QSCALE   (1e-4f / 127.0f)
#define QINV     (127.0f / 1e-4f)

typedef float vf2 __attribute__((ext_vector_type(2)));
typedef float vf4 __attribute__((ext_vector_type(4)));

// ---- prepass: f32 table -> packed int8 pairs.
// dword p of a level = bytes [f0(2p), f1(2p), f0(2p+1), f1(2p+1)]
// -> entries (idx, idx^1) share ONE dword. 16B read / 4B write, coalesced.
__global__ __launch_bounds__(256) void cvt_i8_kernel(
    const vf4* __restrict__ src, unsigned* __restrict__ dst, int npair)
{
    int i = blockIdx.x * blockDim.x + threadIdx.x;
    if (i >= npair) return;
    vf4 v = src[i];            // {f0(2i), f1(2i), f0(2i+1), f1(2i+1)}
    // |v| < 1e-4 strictly (uniform open bound) -> |q| <= 127, no clamp needed
    int q0 = __float2int_rn(v.x * QINV);
    int q1 = __float2int_rn(v.y * QINV);
    int q2 = __float2int_rn(v.z * QINV);
    int q3 = __float2int_rn(v.w * QINV);
    dst[i] = (q0 & 0xff) | ((q1 & 0xff) << 8) | ((q2 & 0xff) << 16) | ((q3 & 0xff) << 24);
}

static __device__ __forceinline__ float i8x(unsigned u) {
    return (float)(signed char)(u & 0xffu) * QSCALE;
}
static __device__ __forceinline__ float i8y(unsigned u) {
    return (float)(signed char)((u >> 8) & 0xffu) * QSCALE;
}
static __device__ __forceinline__ float h2low(unsigned u)  { __half2 h = *reinterpret_cast<__half2*>(&u); return __low2float(h); }
static __device__ __forceinline__ float h2high(unsigned u) { __half2 h = *reinterpret_cast<__half2*>(&u); return __high2float(h); }

// ---- main (R7 structure; table = packed int8 pairs, 1 MB/level).
// xcd = bid&7 owns levels {2*xcd, 2*xcd+1} time-sliced -> one L2-resident
// table per XCD (R4/R7-proven). Dword currency (R1/R2/R5/R6-validated):
// even i0 -> idx10 = idx00^1 = same dword as idx00 -> 2 dwords/point-level;
// odd i0 -> +2 fix-up dwords. Avg 3 vs R7's 4 -> predict main ~0.75x.
__global__ __launch_bounds__(THREADS) void hashgrid2d_lvl_i8(
    const float* __restrict__ x,
    const unsigned* __restrict__ aux,   // [NLEVELS][TENTRIES/2] packed dwords
    unsigned* __restrict__ outT,        // [NLEVELS][B] half2-bits, in ws
    int B, int chunksPerLevel)
{
    int bid  = blockIdx.x;
    int xcd  = bid & 7;
    int seq  = bid >> 3;
    int half = (seq >= chunksPerLevel) ? 1 : 0;
    int level = 2 * xcd + half;
    int chunk = seq - half * chunksPerLevel;

    const unsigned* __restrict__ tblp = aux + ((size_t)level << (LOG2T - 1));
    const vf2* __restrict__ x2 = reinterpret_cast<const vf2*>(x);
    float res = (float)(256 << level);      // exact power of two

    int base = chunk * PTS_PER_BLOCK + (int)threadIdx.x;

    // per point: e**h hold 16 bits [f1:f0] of each corner
    unsigned e00h[PTS_PER_THREAD], e01h[PTS_PER_THREAD], e10h[PTS_PER_THREAD], e11h[PTS_PER_THREAD];
    float w0[PTS_PER_THREAD], w1[PTS_PER_THREAD];
    int   bidx[PTS_PER_THREAD];

    #pragma unroll
    for (int k = 0; k < PTS_PER_THREAD; ++k) {
        int b = base + k * THREADS;
        bidx[k] = b;
        if (b >= B) b = B - 1;              // clamp; store skipped below
        vf2 xy = __builtin_nontemporal_load(&x2[b]);

        float xs0 = xy.x * res;             // exact (pow2 scale)
        float xs1 = xy.y * res;
        float v0 = floorf(xs0), v1 = floorf(xs1);
        w0[k] = xs0 - v0;
        w1[k] = xs1 - v1;

        unsigned i0 = (unsigned)(int)v0;
        unsigned i1 = (unsigned)(int)v1;
        unsigned hy0 = i1 * PRIME1;
        unsigned hy1 = hy0 + PRIME1;        // (i1+1)*PRIME1

        unsigned idx00 = (i0 ^ hy0) & TMASK;
        unsigned idx01 = (i0 ^ hy1) & TMASK;

        unsigned u0 = tblp[idx00 >> 1];     // entries {idx00&~1, idx00|1}
        unsigned u1 = tblp[idx01 >> 1];

        unsigned s0 = idx00 & 1u, s1 = idx01 & 1u;
        e00h[k] = s0 ? (u0 >> 16) : (u0 & 0xffffu);
        e01h[k] = s1 ? (u1 >> 16) : (u1 & 0xffffu);

        if ((i0 & 1u) == 0u) {
            // even: x-neighbor (idx^1) is the other 16-bit half of the dword
            e10h[k] = s0 ? (u0 & 0xffffu) : (u0 >> 16);
            e11h[k] = s1 ? (u1 & 0xffffu) : (u1 >> 16);
        } else {
            // odd: neighbor hashes elsewhere -> 2 masked fix-up dwords
            unsigned idx10 = ((i0 + 1u) ^ hy0) & TMASK;
            unsigned idx11 = ((i0 + 1u) ^ hy1) & TMASK;
            unsigned v10 = tblp[idx10 >> 1];
            unsigned v11 = tblp[idx11 >> 1];
            e10h[k] = (idx10 & 1u) ? (v10 >> 16) : (v10 & 0xffffu);
            e11h[k] = (idx11 & 1u) ? (v11 >> 16) : (v11 & 0xffffu);
        }
    }

    #pragma unroll
    for (int k = 0; k < PTS_PER_THREAD; ++k) {
        int b = bidx[k];
        if (b >= B) continue;
        float omw0 = 1.0f - w0[k], omw1 = 1.0f - w1[k];
        float c0x = i8x(e00h[k]) * omw0 + i8x(e10h[k]) * w0[k];
        float c0y = i8y(e00h[k]) * omw0 + i8y(e10h[k]) * w0[k];
        float c1x = i8x(e01h[k]) * omw0 + i8x(e11h[k]) * w0[k];
        float c1y = i8y(e01h[k]) * omw0 + i8y(e11h[k]) * w0[k];
        float ox = c0x * omw1 + c1x * w1[k];
        float oy = c0y * omw1 + c1y * w1[k];
        __half2 oh = __floats2half2_rn(ox, oy);
        // level-major: consecutive threads -> consecutive b -> coalesced 4B
        __builtin_nontemporal_store(*reinterpret_cast<unsigned*>(&oh),
                                    &outT[(size_t)level * B + b]);
    }
}

// ---- transpose pass: outT[l][b] half2 -> out[b][l] f32, LDS-tiled (R5/R7-proven) ----
__global__ __launch_bounds__(THREADS) void transpose_out(
    const unsigned* __restrict__ outT, vf2* __restrict__ out, int B)
{
    __shared__ unsigned tile[NLEVELS][THREADS + 1];   // pad breaks bank alias
    int base = blockIdx.x * THREADS;
    int t = (int)threadIdx.x;

    #pragma unroll
    for (int l = 0; l < NLEVELS; ++l) {
        int b = base + t;
        if (b < B) tile[l][t] = __builtin_nontemporal_load(&outT[(size_t)l * B + b]);
    }
    __syncthreads();

    int l   = t & 15;
    int sub = t >> 4;
    #pragma unroll
    for (int g = 0; g < NLEVELS; ++g) {
        int i = g * 16 + sub;                    // point within tile
        int b = base + i;
        if (b < B) {
            unsigned u = tile[l][i];
            vf2 o;
            o.x = h2low(u);
            o.y = h2high(u);
            // 16 lanes (l=0..15) cover one b's 128B row -> 512B/wave contiguous
            __builtin_nontemporal_store(o, &out[(size_t)b * NLEVELS + l]);
        }
    }
}

// ---- fallback (R0): pure f32, no workspace needed ----
__global__ __launch_bounds__(256) void hashgrid2d_f32(
    const float* __restrict__ x, const float* __restrict__ tables,
    float* __restrict__ out, int B)
{
    int tid = blockIdx.x * blockDim.x + threadIdx.x;
    int b = tid >> 4;
    if (b >= B) return;
    int l = tid & 15;
    vf2 xy = __builtin_nontemporal_load(reinterpret_cast<const vf2*>(x) + b);
    float res = (float)(256 << l);
    float xs0 = xy.x * res, xs1 = xy.y * res;
    float v0 = floorf(xs0), v1 = floorf(xs1);
    float w0 = xs0 - v0,    w1 = xs1 - v1;
    unsigned i0 = (unsigned)(int)v0, i1 = (unsigned)(int)v1;
    unsigned hy0 = i1 * PRIME1, hy1 = hy0 + PRIME1;
    unsigned idx00 = ( i0       ^ hy0) & TMASK;
    unsigned idx01 = ( i0       ^ hy1) & TMASK;
    unsigned idx10 = ((i0 + 1u) ^ hy0) & TMASK;
    unsigned idx11 = ((i0 + 1u) ^ hy1) & TMASK;
    const vf2* tbl = reinterpret_cast<const vf2*>(tables) + ((size_t)l << LOG2T);
    vf2 e00 = tbl[idx00], e01 = tbl[idx01], e10 = tbl[idx10], e11 = tbl[idx11];
    float omw0 = 1.0f - w0, omw1 = 1.0f - w1;
    float c0x = e00.x * omw0 + e10.x * w0;
    float c0y = e00.y * omw0 + e10.y * w0;
    float c1x = e01.x * omw0 + e11.x * w0;
    float c1y = e01.y * omw0 + e11.y * w0;
    vf2 o;
    o.x = c0x * omw1 + c1x * w1;
    o.y = c0y * omw1 + c1y * w1;
    __builtin_nontemporal_store(o, reinterpret_cast<vf2*>(out) + tid);
}

extern "C" void kernel_launch(void* const* d_in, const int* in_sizes, int n_in,
                              void* d_out, int out_size, void* d_ws, size_t ws_size,
                              hipStream_t stream) {
    const float* x      = (const float*)d_in[0];
    const float* tables = (const float*)d_in[1];
    float* out          = (float*)d_out;
    int B = in_sizes[0] / 2;

    const size_t auxBytes  = (size_t)NLEVELS * TENTRIES * 2;         // 16 MiB int8 table
    const size_t outTBytes = (size_t)B * NLEVELS * sizeof(unsigned); // 64 MB half2 staging

    int block = 256;
    int npair = NLEVELS * TENTRIES / 2;
    int cgrid = (npair + block - 1) / block;

    if (ws_size >= auxBytes + outTBytes) {
        unsigned* aux  = reinterpret_cast<unsigned*>(d_ws);
        unsigned* outT = reinterpret_cast<unsigned*>((char*)d_ws + auxBytes);
        cvt_i8_kernel<<<cgrid, block, 0, stream>>>(
            reinterpret_cast<const vf4*>(tables), aux, npair);
        int chunksPerLevel = (B + PTS_PER_BLOCK - 1) / PTS_PER_BLOCK;
        int mgrid = NLEVELS * chunksPerLevel;
        hashgrid2d_lvl_i8<<<mgrid, THREADS, 0, stream>>>(x, aux, outT, B, chunksPerLevel);
        int tgrid = (B + THREADS - 1) / THREADS;
        transpose_out<<<tgrid, THREADS, 0, stream>>>(outT, reinterpret_cast<vf2*>(out), B);
    } else {
        int total = B * NLEVELS;
        int grid  = (total + block - 1) / block;
        hashgrid2d_f32<<<grid, block, 0, stream>>>(x, tables, out, B);
    }
}

// Round 11
// 215.162 us; speedup vs baseline: 1.2528x; 1.2528x over previous
//
#include <hip/hip_runtime.h>
#include <hip/hip_fp16.h>

#define NLEVELS 16
#define LOG2T 19
#define TENTRIES (1u << LOG2T)
#define TMASK (TENTRIES - 1u)
#define PRIME1 2654435761u
#define THREADS 256
#define PTS_PER_THREAD 8
#define PTS_PER_BLOCK (THREADS * PTS_PER_THREAD)

typedef float vf2 __attribute__((ext_vector_type(2)));
typedef float vf4 __attribute__((ext_vector_type(4)));

// ---- prepass: f32 table -> half2-per-entry table in ws (coalesced, HBM-wall) ----
__global__ __launch_bounds__(256) void cvt_fp16_kernel(
    const vf4* __restrict__ src, uint2* __restrict__ dst, int npair)
{
    int i = blockIdx.x * blockDim.x + threadIdx.x;
    if (i >= npair) return;
    vf4 v = src[i];
    __half2 a = __floats2half2_rn(v.x, v.y);
    __half2 b = __floats2half2_rn(v.z, v.w);
    uint2 o;
    o.x = *reinterpret_cast<unsigned*>(&a);
    o.y = *reinterpret_cast<unsigned*>(&b);
    dst[i] = o;
}

static __device__ __forceinline__ float h2low(unsigned u)  { __half2 h = *reinterpret_cast<__half2*>(&u); return __low2float(h); }
static __device__ __forceinline__ float h2high(unsigned u) { __half2 h = *reinterpret_cast<__half2*>(&u); return __high2float(h); }

// ---- main (R7 structure = best proven, 181us):
// one level per block; xcd = bid&7 owns levels {2*xcd, 2*xcd+1} time-sliced ->
// each XCD's L2 holds one 2MB fp16 table (FETCH 1.9GB -> 76MB proven).
// 4 PLAIN dword gathers per point-level — proven optimal: masked/merged
// variants (R2/R5/R9) all ~25% slower (exec-mask branches serialize issue);
// the even-i0 pair benefit comes free via L1 (e00/e10 4B apart -> L1 hit).
// PTS_PER_THREAD=8: 32-deep gather window (probe; predicted neutral).
__global__ __launch_bounds__(THREADS) void hashgrid2d_lvl_fp16h(
    const float* __restrict__ x,
    const __half2* __restrict__ aux,
    unsigned* __restrict__ outT,        // [NLEVELS][B] half2-bits, in ws
    int B, int chunksPerLevel)
{
    int bid  = blockIdx.x;
    int xcd  = bid & 7;
    int seq  = bid >> 3;
    int half = (seq >= chunksPerLevel) ? 1 : 0;
    int level = 2 * xcd + half;
    int chunk = seq - half * chunksPerLevel;

    const unsigned* __restrict__ tbl1 =
        reinterpret_cast<const unsigned*>(aux) + ((size_t)level << LOG2T);
    const vf2* __restrict__ x2 = reinterpret_cast<const vf2*>(x);
    float res = (float)(256 << level);      // exact power of two

    int base = chunk * PTS_PER_BLOCK + (int)threadIdx.x;

    unsigned e00u[PTS_PER_THREAD], e01u[PTS_PER_THREAD], e10u[PTS_PER_THREAD], e11u[PTS_PER_THREAD];
    float w0[PTS_PER_THREAD], w1[PTS_PER_THREAD];
    int   bidx[PTS_PER_THREAD];

    #pragma unroll
    for (int k = 0; k < PTS_PER_THREAD; ++k) {
        int b = base + k * THREADS;
        bidx[k] = b;
        if (b >= B) b = B - 1;              // clamp; store skipped below
        vf2 xy = __builtin_nontemporal_load(&x2[b]);

        float xs0 = xy.x * res;             // exact (pow2 scale)
        float xs1 = xy.y * res;
        float v0 = floorf(xs0), v1 = floorf(xs1);
        w0[k] = xs0 - v0;
        w1[k] = xs1 - v1;

        unsigned i0 = (unsigned)(int)v0;
        unsigned i1 = (unsigned)(int)v1;
        unsigned hy0 = i1 * PRIME1;
        unsigned hy1 = hy0 + PRIME1;        // (i1+1)*PRIME1

        e00u[k] = tbl1[( i0       ^ hy0) & TMASK];
        e01u[k] = tbl1[( i0       ^ hy1) & TMASK];
        e10u[k] = tbl1[((i0 + 1u) ^ hy0) & TMASK];
        e11u[k] = tbl1[((i0 + 1u) ^ hy1) & TMASK];
    }

    #pragma unroll
    for (int k = 0; k < PTS_PER_THREAD; ++k) {
        int b = bidx[k];
        if (b >= B) continue;
        float omw0 = 1.0f - w0[k], omw1 = 1.0f - w1[k];
        float c0x = h2low(e00u[k])  * omw0 + h2low(e10u[k])  * w0[k];
        float c0y = h2high(e00u[k]) * omw0 + h2high(e10u[k]) * w0[k];
        float c1x = h2low(e01u[k])  * omw0 + h2low(e11u[k])  * w0[k];
        float c1y = h2high(e01u[k]) * omw0 + h2high(e11u[k]) * w0[k];
        float ox = c0x * omw1 + c1x * w1[k];
        float oy = c0y * omw1 + c1y * w1[k];
        __half2 oh = __floats2half2_rn(ox, oy);
        // level-major: consecutive threads -> consecutive b -> coalesced 4B
        __builtin_nontemporal_store(*reinterpret_cast<unsigned*>(&oh),
                                    &outT[(size_t)level * B + b]);
    }
}

// ---- transpose pass: outT[l][b] half2 -> out[b][l] f32, LDS-tiled (HBM-wall) ----
__global__ __launch_bounds__(THREADS) void transpose_out(
    const unsigned* __restrict__ outT, vf2* __restrict__ out, int B)
{
    __shared__ unsigned tile[NLEVELS][THREADS + 1];   // pad breaks bank alias
    int base = blockIdx.x * THREADS;
    int t = (int)threadIdx.x;

    #pragma unroll
    for (int l = 0; l < NLEVELS; ++l) {
        int b = base + t;
        if (b < B) tile[l][t] = __builtin_nontemporal_load(&outT[(size_t)l * B + b]);
    }
    __syncthreads();

    int l   = t & 15;
    int sub = t >> 4;
    #pragma unroll
    for (int g = 0; g < NLEVELS; ++g) {
        int i = g * 16 + sub;                    // point within tile
        int b = base + i;
        if (b < B) {
            unsigned u = tile[l][i];
            vf2 o;
            o.x = h2low(u);
            o.y = h2high(u);
            // 16 lanes (l=0..15) cover one b's 128B row -> 512B/wave contiguous
            __builtin_nontemporal_store(o, &out[(size_t)b * NLEVELS + l]);
        }
    }
}

// ---- fallback (R0): pure f32, no workspace needed ----
__global__ __launch_bounds__(256) void hashgrid2d_f32(
    const float* __restrict__ x, const float* __restrict__ tables,
    float* __restrict__ out, int B)
{
    int tid = blockIdx.x * blockDim.x + threadIdx.x;
    int b = tid >> 4;
    if (b >= B) return;
    int l = tid & 15;
    vf2 xy = __builtin_nontemporal_load(reinterpret_cast<const vf2*>(x) + b);
    float res = (float)(256 << l);
    float xs0 = xy.x * res, xs1 = xy.y * res;
    float v0 = floorf(xs0), v1 = floorf(xs1);
    float w0 = xs0 - v0,    w1 = xs1 - v1;
    unsigned i0 = (unsigned)(int)v0, i1 = (unsigned)(int)v1;
    unsigned hy0 = i1 * PRIME1, hy1 = hy0 + PRIME1;
    unsigned idx00 = ( i0       ^ hy0) & TMASK;
    unsigned idx01 = ( i0       ^ hy1) & TMASK;
    unsigned idx10 = ((i0 + 1u) ^ hy0) & TMASK;
    unsigned idx11 = ((i0 + 1u) ^ hy1) & TMASK;
    const vf2* tbl = reinterpret_cast<const vf2*>(tables) + ((size_t)l << LOG2T);
    vf2 e00 = tbl[idx00], e01 = tbl[idx01], e10 = tbl[idx10], e11 = tbl[idx11];
    float omw0 = 1.0f - w0, omw1 = 1.0f - w1;
    float c0x = e00.x * omw0 + e10.x * w0;
    float c0y = e00.y * omw0 + e10.y * w0;
    float c1x = e01.x * omw0 + e11.x * w0;
    float c1y = e01.y * omw0 + e11.y * w0;
    vf2 o;
    o.x = c0x * omw1 + c1x * w1;
    o.y = c0y * omw1 + c1y * w1;
    __builtin_nontemporal_store(o, reinterpret_cast<vf2*>(out) + tid);
}

extern "C" void kernel_launch(void* const* d_in, const int* in_sizes, int n_in,
                              void* d_out, int out_size, void* d_ws, size_t ws_size,
                              hipStream_t stream) {
    const float* x      = (const float*)d_in[0];
    const float* tables = (const float*)d_in[1];
    float* out          = (float*)d_out;
    int B = in_sizes[0] / 2;

    const size_t auxBytes  = (size_t)NLEVELS * TENTRIES * 4;         // 32 MiB fp16 table
    const size_t outTBytes = (size_t)B * NLEVELS * sizeof(unsigned); // 64 MB half2 staging

    int block = 256;
    int npair = NLEVELS * TENTRIES / 2;
    int cgrid = (npair + block - 1) / block;

    if (ws_size >= auxBytes + outTBytes) {
        __half2* aux = reinterpret_cast<__half2*>(d_ws);
        unsigned* outT = reinterpret_cast<unsigned*>((char*)d_ws + auxBytes);
        cvt_fp16_kernel<<<cgrid, block, 0, stream>>>(
            reinterpret_cast<const vf4*>(tables), reinterpret_cast<uint2*>(aux), npair);
        int chunksPerLevel = (B + PTS_PER_BLOCK - 1) / PTS_PER_BLOCK;
        int mgrid = NLEVELS * chunksPerLevel;
        hashgrid2d_lvl_fp16h<<<mgrid, THREADS, 0, stream>>>(x, aux, outT, B, chunksPerLevel);
        int tgrid = (B + THREADS - 1) / THREADS;
        transpose_out<<<tgrid, THREADS, 0, stream>>>(outT, reinterpret_cast<vf2*>(out), B);
    } else {
        int total = B * NLEVELS;
        int grid  = (total + block - 1) / block;
        hashgrid2d_f32<<<grid, block, 0, stream>>>(x, tables, out, B);
    }
}